// Round 3
// baseline (169.855 us; speedup 1.0000x reference)
//
#include <hip/hip_runtime.h>

typedef _Float16 f16;
typedef f16 f16x4 __attribute__((ext_vector_type(4)));
typedef f16 f16x8 __attribute__((ext_vector_type(8)));
typedef float f32x4 __attribute__((ext_vector_type(4)));

// state_embed (256,512) f32 | action_feats (256,1000,64) f32 | W1 (576,256) | b1 (256)
// W2 (256,128) | b2 (128) | W3 (128,1) | b3 (1)  -> out (256,1000) f32

#define H1_STRIDE 264   // 256+8 f16; 132 dwords/row, 132%32=4 -> 2-way (free)

// ---------- prep: pack W1a^T (A-frag order), W2 (B-frag order), compute h_state ----------
// A-frag (16x16x32): lane L holds A[m=L&15][k=(L>>4)*8+j], j=0..7
// B-frag:            lane L holds B[k=(L>>4)*8+j][n=L&15]
__global__ __launch_bounds__(256) void prep_kernel(const float* __restrict__ W1,
                                                   const float* __restrict__ W2,
                                                   const float* __restrict__ state,
                                                   const float* __restrict__ b1,
                                                   f16* __restrict__ pw1at,
                                                   f16* __restrict__ pw2,
                                                   float* __restrict__ hstate) {
    __shared__ float srow[4][512];
    int blk = blockIdx.x;
    int tid = threadIdx.x;
    if (blk < 24) {
        int idx = blk * 256 + tid;              // 0..6143
        int F = idx >> 6;                       // fragment id 0..95
        int L = idx & 63;
        int q = L >> 4, c = L & 15;
        f16x8 v;
        if (F < 32) {                           // pw1at = W1_a^T as A-frags: M=256h (mt 0..15), K=64f (kt 0..1)
            int mt = F >> 1, kt = F & 1;
            #pragma unroll
            for (int j = 0; j < 8; ++j) {
                int f = kt * 32 + q * 8 + j;    // feat 0..63
                v[j] = (f16)W1[(size_t)(512 + f) * 256 + mt * 16 + c];  // W1a^T[h][f] = W1[512+f][h]
            }
            *(f16x8*)(pw1at + ((size_t)F * 64 + L) * 8) = v;
        } else {                                // pw2 = W2 as B-frags: K=256 (kt 0..7), N=128 (nt 0..7)
            int F2 = F - 32;
            int nt = F2 >> 3, kt = F2 & 7;
            #pragma unroll
            for (int j = 0; j < 8; ++j) {
                int k = kt * 32 + q * 8 + j;
                v[j] = (f16)W2[(size_t)k * 128 + nt * 16 + c];
            }
            *(f16x8*)(pw2 + ((size_t)F2 * 64 + L) * 8) = v;
        }
    } else {
        // h_state = state_embed @ W1[:512] + b1 (fp32 exact), 4 batch rows per block
        int b0 = (blk - 24) * 4;
        #pragma unroll
        for (int i = 0; i < 8; ++i) {
            int e = i * 256 + tid;
            srow[e >> 9][e & 511] = state[(size_t)b0 * 512 + e];
        }
        __syncthreads();
        float bias = b1[tid];
        float a0 = bias, a1 = bias, a2 = bias, a3 = bias;
        for (int f = 0; f < 512; ++f) {
            float wv = W1[(size_t)f * 256 + tid];
            a0 = fmaf(srow[0][f], wv, a0);
            a1 = fmaf(srow[1][f], wv, a1);
            a2 = fmaf(srow[2][f], wv, a2);
            a3 = fmaf(srow[3][f], wv, a3);
        }
        hstate[(size_t)(b0 + 0) * 256 + tid] = a0;
        hstate[(size_t)(b0 + 1) * 256 + tid] = a1;
        hstate[(size_t)(b0 + 2) * 256 + tid] = a2;
        hstate[(size_t)(b0 + 3) * 256 + tid] = a3;
    }
}

// ---------- fused per-row MLP: 64 action-rows per block, no afeat staging ----------
__global__ __launch_bounds__(256, 4) void fused_kernel(const float* __restrict__ afeat,
                                                       const float* __restrict__ hstate,
                                                       const f16* __restrict__ pw1at,
                                                       const f16* __restrict__ pw2,
                                                       const float* __restrict__ b2,
                                                       const float* __restrict__ W3,
                                                       const float* __restrict__ b3,
                                                       float* __restrict__ out) {
    __shared__ f16 h1s[64 * H1_STRIDE];     // 33792 B
    __shared__ float lds3[256];             //  1024 B  -> 34.8 KB total -> 4 blocks/CU

    int tid = threadIdx.x;
    int w = tid >> 6;                // wave 0..3
    int L = tid & 63;
    int q = L >> 4, c = L & 15;
    int r0 = blockIdx.x * 64;

    // ---- A-frags (W1a^T) for this wave's h-slice: h in [64w, 64w+63] ----
    f16x8 a1f[4][2];
    #pragma unroll
    for (int i = 0; i < 4; ++i)
        #pragma unroll
        for (int kt = 0; kt < 2; ++kt)
            a1f[i][kt] = *(const f16x8*)(pw1at + ((size_t)((4 * w + i) * 2 + kt) * 64 + L) * 8);

    // ---- B-frags (afeat^T) built directly from global fp32 ----
    // lane (q,c), frag (nt,kt): afeat[row = r0+16nt+c][f = 32kt+8q .. +7]
    f16x8 bf[4][2];
    #pragma unroll
    for (int nt = 0; nt < 4; ++nt) {
        const float* rowp = afeat + (size_t)(r0 + nt * 16 + c) * 64 + q * 8;
        #pragma unroll
        for (int kt = 0; kt < 2; ++kt) {
            f32x4 lo = *(const f32x4*)(rowp + kt * 32);
            f32x4 hi = *(const f32x4*)(rowp + kt * 32 + 4);
            f16x8 v;
            v[0] = (f16)lo[0]; v[1] = (f16)lo[1]; v[2] = (f16)lo[2]; v[3] = (f16)lo[3];
            v[4] = (f16)hi[0]; v[5] = (f16)hi[1]; v[6] = (f16)hi[2]; v[7] = (f16)hi[3];
            bf[nt][kt] = v;
        }
    }

    // ---- GEMM1 (swapped): h1^T(256x64) = W1a^T @ afeat^T ----
    f32x4 acc1[4][4];
    #pragma unroll
    for (int i = 0; i < 4; ++i)
        #pragma unroll
        for (int nt = 0; nt < 4; ++nt)
            acc1[i][nt] = (f32x4){0.f, 0.f, 0.f, 0.f};

    #pragma unroll
    for (int i = 0; i < 4; ++i)
        #pragma unroll
        for (int nt = 0; nt < 4; ++nt)
            #pragma unroll
            for (int kt = 0; kt < 2; ++kt)
                acc1[i][nt] = __builtin_amdgcn_mfma_f32_16x16x32_f16(
                    a1f[i][kt], bf[nt][kt], acc1[i][nt], 0, 0, 0);

    // ---- epilogue 1: + h_state, relu, f16 -> h1s (vector b64 stores) ----
    int b0i = r0 / 1000;
    int boundary = (b0i + 1) * 1000;
    int b1i = b0i < 255 ? b0i + 1 : 255;
    #pragma unroll
    for (int i = 0; i < 4; ++i) {
        int hbase = (4 * w + i) * 16 + q * 4;               // 4 consecutive h
        f32x4 hsA = *(const f32x4*)(hstate + (size_t)b0i * 256 + hbase);
        f32x4 hsB = *(const f32x4*)(hstate + (size_t)b1i * 256 + hbase);
        #pragma unroll
        for (int nt = 0; nt < 4; ++nt) {
            int rowg = r0 + nt * 16 + c;
            bool sel = rowg >= boundary;
            f16x4 hv;
            #pragma unroll
            for (int reg = 0; reg < 4; ++reg) {
                float v = acc1[i][nt][reg] + (sel ? hsB[reg] : hsA[reg]);
                v = v > 0.f ? v : 0.f;
                hv[reg] = (f16)v;
            }
            *(f16x4*)(h1s + (nt * 16 + c) * H1_STRIDE + hbase) = hv;
        }
    }
    __syncthreads();

    // ---- GEMM2: h2(64x128) = h1(64x256) @ W2; wave w owns h2 cols [32w, 32w+31] ----
    f32x4 acc2[4][2];
    #pragma unroll
    for (int rb = 0; rb < 4; ++rb) {
        acc2[rb][0] = (f32x4){0.f, 0.f, 0.f, 0.f};
        acc2[rb][1] = (f32x4){0.f, 0.f, 0.f, 0.f};
    }
    #pragma unroll
    for (int kt = 0; kt < 8; ++kt) {
        f16x8 a2[4];
        #pragma unroll
        for (int rb = 0; rb < 4; ++rb)
            a2[rb] = *(const f16x8*)(h1s + (rb * 16 + c) * H1_STRIDE + kt * 32 + q * 8);
        #pragma unroll
        for (int ntl = 0; ntl < 2; ++ntl) {
            f16x8 bfr = *(const f16x8*)(pw2 + ((size_t)((w * 2 + ntl) * 8 + kt) * 64 + L) * 8);
            #pragma unroll
            for (int rb = 0; rb < 4; ++rb)
                acc2[rb][ntl] = __builtin_amdgcn_mfma_f32_16x16x32_f16(
                    a2[rb], bfr, acc2[rb][ntl], 0, 0, 0);
        }
    }

    // ---- layer 3 in-register: logit[row] = sum_col relu(acc2+b2[col]) * W3[col] + b3 ----
    float b2v[2], w3v[2];
    #pragma unroll
    for (int ntl = 0; ntl < 2; ++ntl) {
        int col = (w * 2 + ntl) * 16 + c;
        b2v[ntl] = b2[col];
        w3v[ntl] = W3[col];
    }
    #pragma unroll
    for (int rb = 0; rb < 4; ++rb) {
        #pragma unroll
        for (int reg = 0; reg < 4; ++reg) {
            float p = 0.f;
            #pragma unroll
            for (int ntl = 0; ntl < 2; ++ntl) {
                float v = acc2[rb][ntl][reg] + b2v[ntl];
                v = v > 0.f ? v : 0.f;
                p = fmaf(v, w3v[ntl], p);
            }
            p += __shfl_xor(p, 1);
            p += __shfl_xor(p, 2);
            p += __shfl_xor(p, 4);
            p += __shfl_xor(p, 8);
            if (c == 0) lds3[(rb * 16 + q * 4 + reg) * 4 + w] = p;
        }
    }
    __syncthreads();
    if (tid < 64) {
        f32x4 s = *(const f32x4*)(lds3 + tid * 4);
        out[r0 + tid] = s[0] + s[1] + s[2] + s[3] + b3[0];
    }
}

extern "C" void kernel_launch(void* const* d_in, const int* in_sizes, int n_in,
                              void* d_out, int out_size, void* d_ws, size_t ws_size,
                              hipStream_t stream) {
    const float* state = (const float*)d_in[0];
    const float* afeat = (const float*)d_in[1];
    const float* W1    = (const float*)d_in[2];
    const float* b1    = (const float*)d_in[3];
    const float* W2    = (const float*)d_in[4];
    const float* b2    = (const float*)d_in[5];
    const float* W3    = (const float*)d_in[6];
    const float* b3    = (const float*)d_in[7];
    float* out = (float*)d_out;

    // ws: hstate 256KB | pw1at 32KB (16384 f16) | pw2 64KB (32768 f16)
    float* hstate = (float*)d_ws;
    f16* pw1at = (f16*)((char*)d_ws + 65536 * sizeof(float));
    f16* pw2   = pw1at + 16384;

    prep_kernel<<<88, 256, 0, stream>>>(W1, W2, state, b1, pw1at, pw2, hstate);
    fused_kernel<<<4000, 256, 0, stream>>>(afeat, hstate, pw1at, pw2, b2, W3, b3, out);
}